// Round 4
// baseline (28942.065 us; speedup 1.0000x reference)
//
#include <hip/hip_runtime.h>
#include <hip/hip_fp16.h>

// CYK net: L=64, B=32, DIN=D=FFS=512
//   P[cell] = table[cell] @ WcL.T ; Q[cell] = table[cell] @ WcR.T      (stored fp16)
//   node(j,s) = bc + max_k ( P[j,j+k] + Q[j+k+1,j+s] )                 (bf16 hi/lo frag-major)
//   [vals|P|Q] = node @ BigB + biasBig   (bf16x3 MFMA)
// All 63 levels run inside ONE persistent kernel with a global barrier
// (256 blocks <= 256 CUs => co-residency guaranteed; no cooperative launch needed).

#define Lx 64
#define Bb 32
#define CELLSZ (Bb*512)         // 16384 elems per cell tile

typedef __attribute__((ext_vector_type(8))) short short8v;
typedef __attribute__((ext_vector_type(4))) float f32x4;

__device__ __forceinline__ int tri_idx(int a, int c) {
    return a*Lx - (a*(a-1))/2 + (c - a);
}
__device__ __forceinline__ unsigned short f2bf(float x) {
    unsigned u = __float_as_uint(x);
    unsigned r = (u + 0x7FFFu + ((u >> 16) & 1u)) >> 16;
    return (unsigned short)r;
}
__device__ __forceinline__ float bf2f(unsigned short h) {
    return __uint_as_float((unsigned)h << 16);
}
__device__ __forceinline__ size_t frag_i(int r, int c) {
    return (size_t)(r >> 4)*8192 + (c >> 3)*128 + (r & 15)*8 + (c & 7);
}

// global barrier: every block adds 1, spins until count reaches target.
// Monotonic target sequence; counter zeroed by hipMemsetAsync each call.
__device__ __forceinline__ void gbar(int* cnt, int target) {
    __syncthreads();
    __threadfence();                                   // release prior writes (device scope)
    if (threadIdx.x == 0) {
        __hip_atomic_fetch_add(cnt, 1, __ATOMIC_RELEASE, __HIP_MEMORY_SCOPE_AGENT);
        while (__hip_atomic_load(cnt, __ATOMIC_ACQUIRE, __HIP_MEMORY_SCOPE_AGENT) < target)
            __builtin_amdgcn_s_sleep(1);
    }
    __syncthreads();
    __threadfence();                                   // acquire: invalidate stale caches
}

// ---------------- setup kernels ----------------

__global__ void k_zero_lower(float* __restrict__ table) {
    int cell = blockIdx.x >> 4;
    int i = cell >> 6, j = cell & 63;
    if (j >= i) return;
    int sub = blockIdx.x & 15;
    float4* p = (float4*)(table + (size_t)cell*CELLSZ) + sub*256 + threadIdx.x;
    *p = make_float4(0.f,0.f,0.f,0.f);
}

__global__ void k_lengths(const float* __restrict__ xs_mask, float* __restrict__ lengths) {
    int b = threadIdx.x;
    if (b < Bb) {
        float s = 0.f;
        for (int i = 0; i < Lx; ++i) s += xs_mask[i*Bb + b];
        lengths[b] = s;
    }
}

__global__ void k_mask(const float* __restrict__ lengths, float* __restrict__ mask_out) {
    int idx = blockIdx.x*256 + threadIdx.x;
    int b = idx & 31;
    int j = (idx >> 5) & 63;
    int i = idx >> 11;
    mask_out[idx] = (j >= i && (float)j < lengths[b]) ? 1.f : 0.f;
}

__global__ void k_bias(const float* __restrict__ b2, const float* __restrict__ Wc,
                       float* __restrict__ biasBig) {
    int c = blockIdx.x*256 + threadIdx.x;
    if (c >= 1536) return;
    if (c < 512) { biasBig[c] = b2[c]; return; }
    int p = (c - 512) & 511;
    int dofs = (c < 1024) ? 0 : 512;
    float s = 0.f;
    for (int d = 0; d < 512; ++d) s += b2[d] * Wc[p*1024 + dofs + d];
    biasBig[c] = s;
}

__global__ void k_prep_xh(const float* __restrict__ xs_h,
                          unsigned short* __restrict__ xhH, unsigned short* __restrict__ xhL) {
    int gid = blockIdx.x*256 + threadIdx.x;
    int cell = gid >> 14, e = gid & 16383;
    int b = e >> 9, d = e & 511;
    float v = xs_h[gid];
    unsigned short h = f2bf(v);
    size_t fi = (size_t)cell*16384 + frag_i(b, d);
    xhH[fi] = h; xhL[fi] = f2bf(v - bf2f(h));
}

__global__ void k_prep_w1(const float* __restrict__ W1,
                          unsigned short* __restrict__ WH, unsigned short* __restrict__ WL) {
    int gid = blockIdx.x*256 + threadIdx.x;
    int c = gid >> 9, k = gid & 511;
    float v = W1[c*512 + k];
    unsigned short h = f2bf(v);
    size_t fi = frag_i(c, k);
    WH[fi] = h; WL[fi] = f2bf(v - bf2f(h));
}

__global__ void k_prep_b0(const float* __restrict__ Wc,
                          unsigned short* __restrict__ BH, unsigned short* __restrict__ BL) {
    int gid = blockIdx.x*256 + threadIdx.x;
    int c = gid >> 9, k = gid & 511;
    float v = (c < 512) ? Wc[c*1024 + k] : Wc[(c-512)*1024 + 512 + k];
    unsigned short h = f2bf(v);
    size_t fi = frag_i(c, k);
    BH[fi] = h; BL[fi] = f2bf(v - bf2f(h));
}

__global__ void k_gemm_M(const float* __restrict__ W2, const float* __restrict__ Wc,
                         float* __restrict__ BigB) {
    __shared__ float W2s[32][33];
    __shared__ float Wcs[32][33];
    int ftile = blockIdx.x & 15;
    int ptile = blockIdx.x >> 4;
    int f0 = ftile*32, p0 = ptile*32;
    int dofs  = (p0 >= 512) ? 512 : 0;
    int prow0 = (p0 >= 512) ? (p0 - 512) : p0;
    int t = threadIdx.x;
    int ff = t & 31, pg = t >> 5;
    float acc[4] = {0,0,0,0};
    for (int d0 = 0; d0 < 512; d0 += 32) {
        __syncthreads();
        #pragma unroll
        for (int i = 0; i < 4; ++i) {
            int e = t + 256*i;
            int r = e >> 5, cc = e & 31;
            W2s[r][cc] = W2[(d0 + r)*512 + f0 + cc];
            Wcs[r][cc] = Wc[(prow0 + r)*1024 + dofs + d0 + cc];
        }
        __syncthreads();
        #pragma unroll
        for (int dd = 0; dd < 32; ++dd) {
            float w = W2s[dd][ff];
            #pragma unroll
            for (int ii = 0; ii < 4; ++ii)
                acc[ii] += w * Wcs[pg*4 + ii][dd];
        }
    }
    #pragma unroll
    for (int ii = 0; ii < 4; ++ii)
        BigB[(f0 + ff)*1536 + 512 + p0 + pg*4 + ii] = acc[ii];
}

__global__ void k_makeBT(const float* __restrict__ W2, const float* __restrict__ BigB,
                         unsigned short* __restrict__ BTfH, unsigned short* __restrict__ BTfL) {
    int gid = blockIdx.x*256 + threadIdx.x;
    int c = gid >> 9, k = gid & 511;
    float v = (c < 512) ? W2[c*512 + k] : BigB[k*1536 + c];
    unsigned short h = f2bf(v);
    size_t fi = frag_i(c, k);
    BTfH[fi] = h; BTfL[fi] = f2bf(v - bf2f(h));
}

// ---------------- level-0 MFMA GEMMs (wide, regular launches) ----------------
// MODE 0: A=xs_h frag  B=W1f  bias=b1  -> table diag f32 + diag frag hi/lo
// MODE 1: A=diag frag  B=B0f           -> P,Q fp16 at tri(i,i)
template<int MODE, int NCOLS>
__global__ __launch_bounds__(256) void k_mfma(
    const unsigned short* __restrict__ AH, const unsigned short* __restrict__ AL,
    const unsigned short* __restrict__ BH, const unsigned short* __restrict__ BL,
    const float* __restrict__ bias,
    float* __restrict__ table, __half* __restrict__ P, __half* __restrict__ Q,
    unsigned short* __restrict__ outH, unsigned short* __restrict__ outL)
{
    constexpr int CTILES = NCOLS / 256;
    int cell = blockIdx.x / CTILES;
    int ct   = blockIdx.x % CTILES;
    int t = threadIdx.x;
    int w = t >> 6, l = t & 63;
    int l15 = l & 15, lg = l >> 4;
    int c0 = ct*256 + w*64;

    f32x4 acc[2][4];
    #pragma unroll
    for (int i = 0; i < 2; ++i)
        #pragma unroll
        for (int j = 0; j < 4; ++j) acc[i][j] = (f32x4){0.f,0.f,0.f,0.f};

    size_t lane_off = (size_t)lg*128 + l15*8;
    const unsigned short* aH = AH + (size_t)cell*16384 + lane_off;
    const unsigned short* aL = AL + (size_t)cell*16384 + lane_off;
    const unsigned short* bH = BH + (size_t)(c0 >> 4)*8192 + lane_off;
    const unsigned short* bL = BL + (size_t)(c0 >> 4)*8192 + lane_off;

    #pragma unroll 2
    for (int ks = 0; ks < 16; ++ks) {
        int ko = ks * 512;
        short8v ah0 = *(const short8v*)(aH + ko);
        short8v ah1 = *(const short8v*)(aH + ko + 8192);
        short8v al0 = *(const short8v*)(aL + ko);
        short8v al1 = *(const short8v*)(aL + ko + 8192);
        short8v bh[4], bl[4];
        #pragma unroll
        for (int cf = 0; cf < 4; ++cf) {
            bh[cf] = *(const short8v*)(bH + ko + cf*8192);
            bl[cf] = *(const short8v*)(bL + ko + cf*8192);
        }
        #pragma unroll
        for (int cf = 0; cf < 4; ++cf) {
            acc[0][cf] = __builtin_amdgcn_mfma_f32_16x16x32_bf16(ah0, bh[cf], acc[0][cf], 0, 0, 0);
            acc[1][cf] = __builtin_amdgcn_mfma_f32_16x16x32_bf16(ah1, bh[cf], acc[1][cf], 0, 0, 0);
            acc[0][cf] = __builtin_amdgcn_mfma_f32_16x16x32_bf16(al0, bh[cf], acc[0][cf], 0, 0, 0);
            acc[1][cf] = __builtin_amdgcn_mfma_f32_16x16x32_bf16(al1, bh[cf], acc[1][cf], 0, 0, 0);
            acc[0][cf] = __builtin_amdgcn_mfma_f32_16x16x32_bf16(ah0, bl[cf], acc[0][cf], 0, 0, 0);
            acc[1][cf] = __builtin_amdgcn_mfma_f32_16x16x32_bf16(ah1, bl[cf], acc[1][cf], 0, 0, 0);
        }
    }

    #pragma unroll
    for (int cf = 0; cf < 4; ++cf) {
        int c = c0 + cf*16 + l15;
        if (MODE == 0) {
            float bv = bias[c];
            size_t tbl = (size_t)(cell*65)*CELLSZ;
            #pragma unroll
            for (int rb = 0; rb < 2; ++rb)
                #pragma unroll
                for (int j = 0; j < 4; ++j) {
                    int r = rb*16 + lg*4 + j;
                    float v = acc[rb][cf][j] + bv;
                    table[tbl + (size_t)r*512 + c] = v;
                    size_t fi = (size_t)cell*16384 + frag_i(r, c);
                    unsigned short h = f2bf(v);
                    outH[fi] = h; outL[fi] = f2bf(v - bf2f(h));
                }
        } else {
            int tc = tri_idx(cell, cell);
            __half* dst = (c < 512) ? (P + (size_t)tc*CELLSZ) : (Q + (size_t)tc*CELLSZ);
            int cc = c & 511;
            #pragma unroll
            for (int rb = 0; rb < 2; ++rb)
                #pragma unroll
                for (int j = 0; j < 4; ++j) {
                    int r = rb*16 + lg*4 + j;
                    dst[(size_t)r*512 + cc] = __float2half(acc[rb][cf][j]);
                }
        }
    }
}

// ---------------- persistent level loop ----------------
// grid = 256 blocks x 512 threads (8 waves). 2048 waves total.
// Per level: node phase (n*8 wave-jobs), barrier, gemm phase (n*24 wave-jobs), barrier.
__global__ __launch_bounds__(512) void k_levels(
    __half* __restrict__ P, __half* __restrict__ Q,
    unsigned short* __restrict__ nodeH, unsigned short* __restrict__ nodeL,
    const unsigned short* __restrict__ BTfH, const unsigned short* __restrict__ BTfL,
    const float* __restrict__ bc, const float* __restrict__ biasBig,
    float* __restrict__ table, int* __restrict__ cnt)
{
    const int nW = gridDim.x << 3;
    int wave = (blockIdx.x << 3) | (threadIdx.x >> 6);
    int l = threadIdx.x & 63;
    int l15 = l & 15, lg = l >> 4;
    int bar = 0;
    const int nB = gridDim.x;

    for (int s = 1; s < 64; ++s) {
        int n = 64 - s;

        // ---- node phase: job q -> j = q>>3, bq = (q>>2)&1, fb = q&3 ----
        for (int q = wave; q < n*8; q += nW) {
            int j  = q >> 3;
            int fb = q & 3;
            int bq = (q >> 2) & 1;
            int f = fb*128 + 2*l;
            float2 acc[16];
            #pragma unroll
            for (int e = 0; e < 16; ++e) acc[e] = make_float2(-3.4e38f, -3.4e38f);
            int basePt = tri_idx(j, j);
            for (int k = 0; k < s; ++k) {
                const __half* Pp = P + (size_t)(basePt + k)*CELLSZ + f;
                int a = j + k + 1;
                int tQ = a*Lx - (a*(a-1))/2 + (j + s - a);
                const __half* Qp = Q + (size_t)tQ*CELLSZ + f;
                #pragma unroll
                for (int e = 0; e < 16; ++e) {
                    int b = bq*16 + e;
                    float2 vp = __half22float2(*(const __half2*)(Pp + (size_t)b*512));
                    float2 vq = __half22float2(*(const __half2*)(Qp + (size_t)b*512));
                    acc[e].x = fmaxf(acc[e].x, vp.x + vq.x);
                    acc[e].y = fmaxf(acc[e].y, vp.y + vq.y);
                }
            }
            float bc0 = bc[f], bc1 = bc[f+1];
            #pragma unroll
            for (int e = 0; e < 16; ++e) {
                int b = bq*16 + e;
                float v0 = acc[e].x + bc0;
                float v1 = acc[e].y + bc1;
                unsigned short h0 = f2bf(v0), h1 = f2bf(v1);
                size_t fi = (size_t)j*16384 + frag_i(b, f);
                *(unsigned*)(nodeH + fi) = (unsigned)h0 | ((unsigned)h1 << 16);
                unsigned short lo0 = f2bf(v0 - bf2f(h0)), lo1 = f2bf(v1 - bf2f(h1));
                *(unsigned*)(nodeL + fi) = (unsigned)lo0 | ((unsigned)lo1 << 16);
            }
        }
        gbar(cnt, (++bar)*nB);

        // ---- gemm phase: job q -> cell = q/24, 64-col tile ct = q%24 ----
        int njobs = n*24;
        for (int q = wave; q < njobs; q += nW) {
            int cell = q / 24;
            int ct   = q - cell*24;
            int c0   = ct*64;

            f32x4 acc[2][4];
            #pragma unroll
            for (int i = 0; i < 2; ++i)
                #pragma unroll
                for (int j2 = 0; j2 < 4; ++j2) acc[i][j2] = (f32x4){0.f,0.f,0.f,0.f};

            size_t lane_off = (size_t)lg*128 + l15*8;
            const unsigned short* aH = nodeH + (size_t)cell*16384 + lane_off;
            const unsigned short* aL = nodeL + (size_t)cell*16384 + lane_off;
            const unsigned short* bH = BTfH + (size_t)(c0 >> 4)*8192 + lane_off;
            const unsigned short* bL = BTfL + (size_t)(c0 >> 4)*8192 + lane_off;

            #pragma unroll 2
            for (int ks = 0; ks < 16; ++ks) {
                int ko = ks * 512;
                short8v ah0 = *(const short8v*)(aH + ko);
                short8v ah1 = *(const short8v*)(aH + ko + 8192);
                short8v al0 = *(const short8v*)(aL + ko);
                short8v al1 = *(const short8v*)(aL + ko + 8192);
                short8v bh[4], bl[4];
                #pragma unroll
                for (int cf = 0; cf < 4; ++cf) {
                    bh[cf] = *(const short8v*)(bH + ko + cf*8192);
                    bl[cf] = *(const short8v*)(bL + ko + cf*8192);
                }
                #pragma unroll
                for (int cf = 0; cf < 4; ++cf) {
                    acc[0][cf] = __builtin_amdgcn_mfma_f32_16x16x32_bf16(ah0, bh[cf], acc[0][cf], 0, 0, 0);
                    acc[1][cf] = __builtin_amdgcn_mfma_f32_16x16x32_bf16(ah1, bh[cf], acc[1][cf], 0, 0, 0);
                    acc[0][cf] = __builtin_amdgcn_mfma_f32_16x16x32_bf16(al0, bh[cf], acc[0][cf], 0, 0, 0);
                    acc[1][cf] = __builtin_amdgcn_mfma_f32_16x16x32_bf16(al1, bh[cf], acc[1][cf], 0, 0, 0);
                    acc[0][cf] = __builtin_amdgcn_mfma_f32_16x16x32_bf16(ah0, bl[cf], acc[0][cf], 0, 0, 0);
                    acc[1][cf] = __builtin_amdgcn_mfma_f32_16x16x32_bf16(ah1, bl[cf], acc[1][cf], 0, 0, 0);
                }
            }

            int tc = tri_idx(cell, cell) + s;
            size_t tbl = (size_t)(cell*64 + cell + s)*CELLSZ;
            #pragma unroll
            for (int cf = 0; cf < 4; ++cf) {
                int c = c0 + cf*16 + l15;
                float bv = biasBig[c];
                #pragma unroll
                for (int rb = 0; rb < 2; ++rb)
                    #pragma unroll
                    for (int j2 = 0; j2 < 4; ++j2) {
                        int r = rb*16 + lg*4 + j2;
                        float v = acc[rb][cf][j2] + bv;
                        if (c < 512)       table[tbl + (size_t)r*512 + c] = v;
                        else if (c < 1024) P[(size_t)tc*CELLSZ + (size_t)r*512 + (c-512)]  = __float2half(v);
                        else               Q[(size_t)tc*CELLSZ + (size_t)r*512 + (c-1024)] = __float2half(v);
                    }
            }
        }
        gbar(cnt, (++bar)*nB);
    }
}

// ---------------- launch ----------------

extern "C" void kernel_launch(void* const* d_in, const int* in_sizes, int n_in,
                              void* d_out, int out_size, void* d_ws, size_t ws_size,
                              hipStream_t stream) {
    const float* xs_h    = (const float*)d_in[0];
    const float* xs_mask = (const float*)d_in[1];
    const float* W1      = (const float*)d_in[2];
    const float* b1      = (const float*)d_in[3];
    const float* Wc      = (const float*)d_in[4];
    const float* bc      = (const float*)d_in[5];
    const float* W2      = (const float*)d_in[6];
    const float* b2      = (const float*)d_in[7];

    float* table   = (float*)d_out;                     // 64*64*32*512 f32
    float* maskout = table + 67108864;                  // 64*64*32

    __half* P = (__half*)d_ws;                          // 2080*16384 halves
    __half* Q = P + 34078720;
    unsigned short* nodeH = (unsigned short*)(Q + 34078720);   // 63*16384
    unsigned short* nodeL = nodeH + 1032192;
    unsigned short* xhH   = nodeL + 1032192;            // 64*16384
    unsigned short* xhL   = xhH + 1048576;
    unsigned short* diagH = xhL + 1048576;              // 64*16384
    unsigned short* diagL = diagH + 1048576;
    unsigned short* W1fH  = diagL + 1048576;            // 512*512
    unsigned short* W1fL  = W1fH + 262144;
    unsigned short* B0fH  = W1fL + 262144;              // 1024*512
    unsigned short* B0fL  = B0fH + 524288;
    unsigned short* BTfH  = B0fL + 524288;              // 1536*512
    unsigned short* BTfL  = BTfH + 786432;
    float* BigB    = (float*)(BTfL + 786432);           // 512*1536 f32
    float* biasBig = BigB + 786432;                     // 1536
    float* lengths = biasBig + 1536;                    // 32
    int*   cnt     = (int*)(lengths + 32);              // global barrier counter

    hipMemsetAsync(cnt, 0, 4, stream);
    k_zero_lower<<<65536, 256, 0, stream>>>(table);
    k_lengths<<<1, 64, 0, stream>>>(xs_mask, lengths);
    k_mask<<<512, 256, 0, stream>>>(lengths, maskout);
    k_prep_xh<<<4096, 256, 0, stream>>>(xs_h, xhH, xhL);
    k_prep_w1<<<1024, 256, 0, stream>>>(W1, W1fH, W1fL);
    k_prep_b0<<<2048, 256, 0, stream>>>(Wc, B0fH, B0fL);
    k_gemm_M<<<512, 256, 0, stream>>>(W2, Wc, BigB);
    k_bias<<<6, 256, 0, stream>>>(b2, Wc, biasBig);
    k_makeBT<<<3072, 256, 0, stream>>>(W2, BigB, BTfH, BTfL);

    // level 0: diag (emits frag-major diag too), then P/Q projections
    k_mfma<0, 512><<<64*2, 256, 0, stream>>>(xhH, xhL, W1fH, W1fL, b1,
                                             table, nullptr, nullptr, diagH, diagL);
    k_mfma<1, 1024><<<64*4, 256, 0, stream>>>(diagH, diagL, B0fH, B0fL, nullptr,
                                              table, P, Q, nullptr, nullptr);

    // levels 1..63 in one persistent kernel
    k_levels<<<256, 512, 0, stream>>>(P, Q, nodeH, nodeL, BTfH, BTfL,
                                      bc, biasBig, table, cnt);
}

// Round 6
// 4361.146 us; speedup vs baseline: 6.6363x; 6.6363x over previous
//
#include <hip/hip_runtime.h>
#include <hip/hip_fp16.h>

// CYK net: L=64, B=32, DIN=D=FFS=512
//   P[cell] = table[cell] @ WcL.T ; Q[cell] = table[cell] @ WcR.T      (stored fp16)
//   node(j,s) = bc + max_k ( P[j,j+k] + Q[j+k+1,j+s] )                 (bf16 hi/lo frag-major)
//   [vals|P|Q] = node @ BigB + biasBig   (bf16x3 MFMA)
// Levels 1..63 inside ONE persistent kernel (256 blocks <= 256 CUs, co-resident).
// Barrier: RELEASE add once + RELAXED spin + ONE acquire fence at exit.
// (R4 bug: acquire-load spin emitted buffer_inv per poll -> L2 invalidate storm.)
// Packed f16 ops via inline asm (ROCm 7.2 header lacks usable __hmax2 overload).

#define Lx 64
#define Bb 32
#define CELLSZ (Bb*512)         // 16384 elems per cell tile

typedef __attribute__((ext_vector_type(8))) short short8v;
typedef __attribute__((ext_vector_type(4))) float f32x4;

__device__ __forceinline__ int tri_idx(int a, int c) {
    return a*Lx - (a*(a-1))/2 + (c - a);
}
__device__ __forceinline__ unsigned short f2bf(float x) {
    unsigned u = __float_as_uint(x);
    unsigned r = (u + 0x7FFFu + ((u >> 16) & 1u)) >> 16;
    return (unsigned short)r;
}
__device__ __forceinline__ float bf2f(unsigned short h) {
    return __uint_as_float((unsigned)h << 16);
}
__device__ __forceinline__ size_t frag_i(int r, int c) {
    return (size_t)(r >> 4)*8192 + (c >> 3)*128 + (r & 15)*8 + (c & 7);
}
__device__ __forceinline__ unsigned pk_add_f16(unsigned a, unsigned b) {
    unsigned r;
    asm("v_pk_add_f16 %0, %1, %2" : "=v"(r) : "v"(a), "v"(b));
    return r;
}
__device__ __forceinline__ unsigned pk_max_f16(unsigned a, unsigned b) {
    unsigned r;
    asm("v_pk_max_f16 %0, %1, %2" : "=v"(r) : "v"(a), "v"(b));
    return r;
}
__device__ __forceinline__ float2 h2_to_f2(unsigned u) {
    __half2 h;
    *reinterpret_cast<unsigned*>(&h) = u;
    return __half22float2(h);
}

// global barrier: release-add once, relaxed spin (no per-poll invalidate),
// single acquire fence after exit.
__device__ __forceinline__ void gbar(int* cnt, int target) {
    __syncthreads();
    if (threadIdx.x == 0) {
        __hip_atomic_fetch_add(cnt, 1, __ATOMIC_RELEASE, __HIP_MEMORY_SCOPE_AGENT);
        while (__hip_atomic_load(cnt, __ATOMIC_RELAXED, __HIP_MEMORY_SCOPE_AGENT) < target)
            __builtin_amdgcn_s_sleep(2);
        __builtin_amdgcn_fence(__ATOMIC_ACQUIRE, "agent");
    }
    __syncthreads();
}

// ---------------- setup kernels ----------------

__global__ void k_zero_lower(float* __restrict__ table) {
    int cell = blockIdx.x >> 4;
    int i = cell >> 6, j = cell & 63;
    if (j >= i) return;
    int sub = blockIdx.x & 15;
    float4* p = (float4*)(table + (size_t)cell*CELLSZ) + sub*256 + threadIdx.x;
    *p = make_float4(0.f,0.f,0.f,0.f);
}

__global__ void k_lengths(const float* __restrict__ xs_mask, float* __restrict__ lengths) {
    int b = threadIdx.x;
    if (b < Bb) {
        float s = 0.f;
        for (int i = 0; i < Lx; ++i) s += xs_mask[i*Bb + b];
        lengths[b] = s;
    }
}

__global__ void k_mask(const float* __restrict__ lengths, float* __restrict__ mask_out) {
    int idx = blockIdx.x*256 + threadIdx.x;
    int b = idx & 31;
    int j = (idx >> 5) & 63;
    int i = idx >> 11;
    mask_out[idx] = (j >= i && (float)j < lengths[b]) ? 1.f : 0.f;
}

__global__ void k_bias(const float* __restrict__ b2, const float* __restrict__ Wc,
                       float* __restrict__ biasBig) {
    int c = blockIdx.x*256 + threadIdx.x;
    if (c >= 1536) return;
    if (c < 512) { biasBig[c] = b2[c]; return; }
    int p = (c - 512) & 511;
    int dofs = (c < 1024) ? 0 : 512;
    float s = 0.f;
    for (int d = 0; d < 512; ++d) s += b2[d] * Wc[p*1024 + dofs + d];
    biasBig[c] = s;
}

__global__ void k_prep_xh(const float* __restrict__ xs_h,
                          unsigned short* __restrict__ xhH, unsigned short* __restrict__ xhL) {
    int gid = blockIdx.x*256 + threadIdx.x;
    int cell = gid >> 14, e = gid & 16383;
    int b = e >> 9, d = e & 511;
    float v = xs_h[gid];
    unsigned short h = f2bf(v);
    size_t fi = (size_t)cell*16384 + frag_i(b, d);
    xhH[fi] = h; xhL[fi] = f2bf(v - bf2f(h));
}

__global__ void k_prep_w1(const float* __restrict__ W1,
                          unsigned short* __restrict__ WH, unsigned short* __restrict__ WL) {
    int gid = blockIdx.x*256 + threadIdx.x;
    int c = gid >> 9, k = gid & 511;
    float v = W1[c*512 + k];
    unsigned short h = f2bf(v);
    size_t fi = frag_i(c, k);
    WH[fi] = h; WL[fi] = f2bf(v - bf2f(h));
}

__global__ void k_prep_b0(const float* __restrict__ Wc,
                          unsigned short* __restrict__ BH, unsigned short* __restrict__ BL) {
    int gid = blockIdx.x*256 + threadIdx.x;
    int c = gid >> 9, k = gid & 511;
    float v = (c < 512) ? Wc[c*1024 + k] : Wc[(c-512)*1024 + 512 + k];
    unsigned short h = f2bf(v);
    size_t fi = frag_i(c, k);
    BH[fi] = h; BL[fi] = f2bf(v - bf2f(h));
}

__global__ void k_gemm_M(const float* __restrict__ W2, const float* __restrict__ Wc,
                         float* __restrict__ BigB) {
    __shared__ float W2s[32][33];
    __shared__ float Wcs[32][33];
    int ftile = blockIdx.x & 15;
    int ptile = blockIdx.x >> 4;
    int f0 = ftile*32, p0 = ptile*32;
    int dofs  = (p0 >= 512) ? 512 : 0;
    int prow0 = (p0 >= 512) ? (p0 - 512) : p0;
    int t = threadIdx.x;
    int ff = t & 31, pg = t >> 5;
    float acc[4] = {0,0,0,0};
    for (int d0 = 0; d0 < 512; d0 += 32) {
        __syncthreads();
        #pragma unroll
        for (int i = 0; i < 4; ++i) {
            int e = t + 256*i;
            int r = e >> 5, cc = e & 31;
            W2s[r][cc] = W2[(d0 + r)*512 + f0 + cc];
            Wcs[r][cc] = Wc[(prow0 + r)*1024 + dofs + d0 + cc];
        }
        __syncthreads();
        #pragma unroll
        for (int dd = 0; dd < 32; ++dd) {
            float w = W2s[dd][ff];
            #pragma unroll
            for (int ii = 0; ii < 4; ++ii)
                acc[ii] += w * Wcs[pg*4 + ii][dd];
        }
    }
    #pragma unroll
    for (int ii = 0; ii < 4; ++ii)
        BigB[(f0 + ff)*1536 + 512 + p0 + pg*4 + ii] = acc[ii];
}

__global__ void k_makeBT(const float* __restrict__ W2, const float* __restrict__ BigB,
                         unsigned short* __restrict__ BTfH, unsigned short* __restrict__ BTfL) {
    int gid = blockIdx.x*256 + threadIdx.x;
    int c = gid >> 9, k = gid & 511;
    float v = (c < 512) ? W2[c*512 + k] : BigB[k*1536 + c];
    unsigned short h = f2bf(v);
    size_t fi = frag_i(c, k);
    BTfH[fi] = h; BTfL[fi] = f2bf(v - bf2f(h));
}

// ---------------- level-0 MFMA GEMMs ----------------
template<int MODE, int NCOLS>
__global__ __launch_bounds__(256) void k_mfma(
    const unsigned short* __restrict__ AH, const unsigned short* __restrict__ AL,
    const unsigned short* __restrict__ BH, const unsigned short* __restrict__ BL,
    const float* __restrict__ bias,
    float* __restrict__ table, __half* __restrict__ P, __half* __restrict__ Q,
    unsigned short* __restrict__ outH, unsigned short* __restrict__ outL)
{
    constexpr int CTILES = NCOLS / 256;
    int cell = blockIdx.x / CTILES;
    int ct   = blockIdx.x % CTILES;
    int t = threadIdx.x;
    int w = t >> 6, l = t & 63;
    int l15 = l & 15, lg = l >> 4;
    int c0 = ct*256 + w*64;

    f32x4 acc[2][4];
    #pragma unroll
    for (int i = 0; i < 2; ++i)
        #pragma unroll
        for (int j = 0; j < 4; ++j) acc[i][j] = (f32x4){0.f,0.f,0.f,0.f};

    size_t lane_off = (size_t)lg*128 + l15*8;
    const unsigned short* aH = AH + (size_t)cell*16384 + lane_off;
    const unsigned short* aL = AL + (size_t)cell*16384 + lane_off;
    const unsigned short* bH = BH + (size_t)(c0 >> 4)*8192 + lane_off;
    const unsigned short* bL = BL + (size_t)(c0 >> 4)*8192 + lane_off;

    #pragma unroll 2
    for (int ks = 0; ks < 16; ++ks) {
        int ko = ks * 512;
        short8v ah0 = *(const short8v*)(aH + ko);
        short8v ah1 = *(const short8v*)(aH + ko + 8192);
        short8v al0 = *(const short8v*)(aL + ko);
        short8v al1 = *(const short8v*)(aL + ko + 8192);
        short8v bh[4], bl[4];
        #pragma unroll
        for (int cf = 0; cf < 4; ++cf) {
            bh[cf] = *(const short8v*)(bH + ko + cf*8192);
            bl[cf] = *(const short8v*)(bL + ko + cf*8192);
        }
        #pragma unroll
        for (int cf = 0; cf < 4; ++cf) {
            acc[0][cf] = __builtin_amdgcn_mfma_f32_16x16x32_bf16(ah0, bh[cf], acc[0][cf], 0, 0, 0);
            acc[1][cf] = __builtin_amdgcn_mfma_f32_16x16x32_bf16(ah1, bh[cf], acc[1][cf], 0, 0, 0);
            acc[0][cf] = __builtin_amdgcn_mfma_f32_16x16x32_bf16(al0, bh[cf], acc[0][cf], 0, 0, 0);
            acc[1][cf] = __builtin_amdgcn_mfma_f32_16x16x32_bf16(al1, bh[cf], acc[1][cf], 0, 0, 0);
            acc[0][cf] = __builtin_amdgcn_mfma_f32_16x16x32_bf16(ah0, bl[cf], acc[0][cf], 0, 0, 0);
            acc[1][cf] = __builtin_amdgcn_mfma_f32_16x16x32_bf16(ah1, bl[cf], acc[1][cf], 0, 0, 0);
        }
    }

    #pragma unroll
    for (int cf = 0; cf < 4; ++cf) {
        int c = c0 + cf*16 + l15;
        if (MODE == 0) {
            float bv = bias[c];
            size_t tbl = (size_t)(cell*65)*CELLSZ;
            #pragma unroll
            for (int rb = 0; rb < 2; ++rb)
                #pragma unroll
                for (int j = 0; j < 4; ++j) {
                    int r = rb*16 + lg*4 + j;
                    float v = acc[rb][cf][j] + bv;
                    table[tbl + (size_t)r*512 + c] = v;
                    size_t fi = (size_t)cell*16384 + frag_i(r, c);
                    unsigned short h = f2bf(v);
                    outH[fi] = h; outL[fi] = f2bf(v - bf2f(h));
                }
        } else {
            int tc = tri_idx(cell, cell);
            __half* dst = (c < 512) ? (P + (size_t)tc*CELLSZ) : (Q + (size_t)tc*CELLSZ);
            int cc = c & 511;
            #pragma unroll
            for (int rb = 0; rb < 2; ++rb)
                #pragma unroll
                for (int j = 0; j < 4; ++j) {
                    int r = rb*16 + lg*4 + j;
                    dst[(size_t)r*512 + cc] = __float2half(acc[rb][cf][j]);
                }
        }
    }
}

// ---------------- persistent level loop ----------------
// grid = 256 blocks x 512 threads (8 waves, 2048 waves total).
__global__ __launch_bounds__(512) void k_levels(
    __half* __restrict__ P, __half* __restrict__ Q,
    unsigned short* __restrict__ nodeH, unsigned short* __restrict__ nodeL,
    const unsigned short* __restrict__ BTfH, const unsigned short* __restrict__ BTfL,
    const float* __restrict__ bc, const float* __restrict__ biasBig,
    float* __restrict__ table, int* __restrict__ cnt)
{
    const int nW = gridDim.x << 3;
    int wave = (blockIdx.x << 3) | (threadIdx.x >> 6);
    int l = threadIdx.x & 63;
    int l15 = l & 15, lg = l >> 4;
    int bar = 0;
    const int nB = gridDim.x;

    for (int s = 1; s < 64; ++s) {
        int n = 64 - s;

        // ---- node phase: job q -> j = q>>3, b-chunk bq = q&7 (4 b's); lane owns 8 f ----
        for (int q = wave; q < n*8; q += nW) {
            int j  = q >> 3;
            int b0 = (q & 7) * 4;
            int f0 = l * 8;
            unsigned acc[4][4];
            #pragma unroll
            for (int b4 = 0; b4 < 4; ++b4)
                #pragma unroll
                for (int e = 0; e < 4; ++e) acc[b4][e] = 0xFC00FC00u;   // (-inf, -inf)

            int basePt = tri_idx(j, j);
            for (int k = 0; k < s; ++k) {
                const __half* Pp = P + (size_t)(basePt + k)*CELLSZ + f0;
                int a = j + k + 1;
                int tQ = a*Lx - (a*(a-1))/2 + (j + s - a);
                const __half* Qp = Q + (size_t)tQ*CELLSZ + f0;
                #pragma unroll
                for (int b4 = 0; b4 < 4; ++b4) {
                    int b = b0 + b4;
                    uint4 vp = *(const uint4*)(Pp + (size_t)b*512);
                    uint4 vq = *(const uint4*)(Qp + (size_t)b*512);
                    acc[b4][0] = pk_max_f16(acc[b4][0], pk_add_f16(vp.x, vq.x));
                    acc[b4][1] = pk_max_f16(acc[b4][1], pk_add_f16(vp.y, vq.y));
                    acc[b4][2] = pk_max_f16(acc[b4][2], pk_add_f16(vp.z, vq.z));
                    acc[b4][3] = pk_max_f16(acc[b4][3], pk_add_f16(vp.w, vq.w));
                }
            }
            float4 bcA = *(const float4*)(bc + f0);
            float4 bcB = *(const float4*)(bc + f0 + 4);
            float bcv[8] = {bcA.x,bcA.y,bcA.z,bcA.w,bcB.x,bcB.y,bcB.z,bcB.w};
            #pragma unroll
            for (int b4 = 0; b4 < 4; ++b4) {
                int b = b0 + b4;
                float v[8];
                #pragma unroll
                for (int e = 0; e < 4; ++e) {
                    float2 x = h2_to_f2(acc[b4][e]);
                    v[2*e]   = x.x + bcv[2*e];
                    v[2*e+1] = x.y + bcv[2*e+1];
                }
                unsigned uh[4], ul[4];
                #pragma unroll
                for (int e = 0; e < 4; ++e) {
                    unsigned short h0 = f2bf(v[2*e]),  h1 = f2bf(v[2*e+1]);
                    unsigned short o0 = f2bf(v[2*e] - bf2f(h0));
                    unsigned short o1 = f2bf(v[2*e+1] - bf2f(h1));
                    uh[e] = (unsigned)h0 | ((unsigned)h1 << 16);
                    ul[e] = (unsigned)o0 | ((unsigned)o1 << 16);
                }
                size_t fi = (size_t)j*16384 + frag_i(b, f0);
                *(uint4*)(nodeH + fi) = make_uint4(uh[0],uh[1],uh[2],uh[3]);
                *(uint4*)(nodeL + fi) = make_uint4(ul[0],ul[1],ul[2],ul[3]);
            }
        }
        gbar(cnt, (++bar)*nB);

        // ---- gemm phase: job q -> cell = q/24, 64-col tile ct = q%24 ----
        int njobs = n*24;
        for (int q = wave; q < njobs; q += nW) {
            int cell = q / 24;
            int ct   = q - cell*24;
            int c0   = ct*64;

            f32x4 acc[2][4];
            #pragma unroll
            for (int i = 0; i < 2; ++i)
                #pragma unroll
                for (int j2 = 0; j2 < 4; ++j2) acc[i][j2] = (f32x4){0.f,0.f,0.f,0.f};

            size_t lane_off = (size_t)lg*128 + l15*8;
            const unsigned short* aH = nodeH + (size_t)cell*16384 + lane_off;
            const unsigned short* aL = nodeL + (size_t)cell*16384 + lane_off;
            const unsigned short* bH = BTfH + (size_t)(c0 >> 4)*8192 + lane_off;
            const unsigned short* bL = BTfL + (size_t)(c0 >> 4)*8192 + lane_off;

            #pragma unroll 2
            for (int ks = 0; ks < 16; ++ks) {
                int ko = ks * 512;
                short8v ah0 = *(const short8v*)(aH + ko);
                short8v ah1 = *(const short8v*)(aH + ko + 8192);
                short8v al0 = *(const short8v*)(aL + ko);
                short8v al1 = *(const short8v*)(aL + ko + 8192);
                short8v bh[4], bl[4];
                #pragma unroll
                for (int cf = 0; cf < 4; ++cf) {
                    bh[cf] = *(const short8v*)(bH + ko + cf*8192);
                    bl[cf] = *(const short8v*)(bL + ko + cf*8192);
                }
                #pragma unroll
                for (int cf = 0; cf < 4; ++cf) {
                    acc[0][cf] = __builtin_amdgcn_mfma_f32_16x16x32_bf16(ah0, bh[cf], acc[0][cf], 0, 0, 0);
                    acc[1][cf] = __builtin_amdgcn_mfma_f32_16x16x32_bf16(ah1, bh[cf], acc[1][cf], 0, 0, 0);
                    acc[0][cf] = __builtin_amdgcn_mfma_f32_16x16x32_bf16(al0, bh[cf], acc[0][cf], 0, 0, 0);
                    acc[1][cf] = __builtin_amdgcn_mfma_f32_16x16x32_bf16(al1, bh[cf], acc[1][cf], 0, 0, 0);
                    acc[0][cf] = __builtin_amdgcn_mfma_f32_16x16x32_bf16(ah0, bl[cf], acc[0][cf], 0, 0, 0);
                    acc[1][cf] = __builtin_amdgcn_mfma_f32_16x16x32_bf16(ah1, bl[cf], acc[1][cf], 0, 0, 0);
                }
            }

            int tc = tri_idx(cell, cell) + s;
            size_t tbl = (size_t)(cell*64 + cell + s)*CELLSZ;
            #pragma unroll
            for (int cf = 0; cf < 4; ++cf) {
                int c = c0 + cf*16 + l15;
                float bv = biasBig[c];
                #pragma unroll
                for (int rb = 0; rb < 2; ++rb)
                    #pragma unroll
                    for (int j2 = 0; j2 < 4; ++j2) {
                        int r = rb*16 + lg*4 + j2;
                        float v = acc[rb][cf][j2] + bv;
                        if (c < 512)       table[tbl + (size_t)r*512 + c] = v;
                        else if (c < 1024) P[(size_t)tc*CELLSZ + (size_t)r*512 + (c-512)]  = __float2half(v);
                        else               Q[(size_t)tc*CELLSZ + (size_t)r*512 + (c-1024)] = __float2half(v);
                    }
            }
        }
        gbar(cnt, (++bar)*nB);
    }
}

// ---------------- launch ----------------

extern "C" void kernel_launch(void* const* d_in, const int* in_sizes, int n_in,
                              void* d_out, int out_size, void* d_ws, size_t ws_size,
                              hipStream_t stream) {
    const float* xs_h    = (const float*)d_in[0];
    const float* xs_mask = (const float*)d_in[1];
    const float* W1      = (const float*)d_in[2];
    const float* b1      = (const float*)d_in[3];
    const float* Wc      = (const float*)d_in[4];
    const float* bc      = (const float*)d_in[5];
    const float* W2      = (const float*)d_in[6];
    const float* b2      = (const float*)d_in[7];

    float* table   = (float*)d_out;                     // 64*64*32*512 f32
    float* maskout = table + 67108864;                  // 64*64*32

    __half* P = (__half*)d_ws;                          // 2080*16384 halves
    __half* Q = P + 34078720;
    unsigned short* nodeH = (unsigned short*)(Q + 34078720);   // 63*16384
    unsigned short* nodeL = nodeH + 1032192;
    unsigned short* xhH   = nodeL + 1032192;            // 64*16384
    unsigned short* xhL   = xhH + 1048576;
    unsigned short* diagH = xhL + 1048576;              // 64*16384
    unsigned short* diagL = diagH + 1048576;
    unsigned short* W1fH  = diagL + 1048576;            // 512*512
    unsigned short* W1fL  = W1fH + 262144;
    unsigned short* B0fH  = W1fL + 262144;              // 1024*512
    unsigned short* B0fL  = B0fH + 524288;
    unsigned short* BTfH  = B0fL + 524288;              // 1536*512
    unsigned short* BTfL  = BTfH + 786432;
    float* BigB    = (float*)(BTfL + 786432);           // 512*1536 f32
    float* biasBig = BigB + 786432;                     // 1536
    float* lengths = biasBig + 1536;                    // 32
    int*   cnt     = (int*)(lengths + 32);              // global barrier counter

    (void)hipMemsetAsync(cnt, 0, 4, stream);
    k_zero_lower<<<65536, 256, 0, stream>>>(table);
    k_lengths<<<1, 64, 0, stream>>>(xs_mask, lengths);
    k_mask<<<512, 256, 0, stream>>>(lengths, maskout);
    k_prep_xh<<<4096, 256, 0, stream>>>(xs_h, xhH, xhL);
    k_prep_w1<<<1024, 256, 0, stream>>>(W1, W1fH, W1fL);
    k_prep_b0<<<2048, 256, 0, stream>>>(Wc, B0fH, B0fL);
    k_gemm_M<<<512, 256, 0, stream>>>(W2, Wc, BigB);
    k_bias<<<6, 256, 0, stream>>>(b2, Wc, biasBig);
    k_makeBT<<<3072, 256, 0, stream>>>(W2, BigB, BTfH, BTfL);

    // level 0: diag (emits frag-major diag too), then P/Q projections
    k_mfma<0, 512><<<64*2, 256, 0, stream>>>(xhH, xhL, W1fH, W1fL, b1,
                                             table, nullptr, nullptr, diagH, diagL);
    k_mfma<1, 1024><<<64*4, 256, 0, stream>>>(diagH, diagL, B0fH, B0fL, nullptr,
                                              table, P, Q, nullptr, nullptr);

    // levels 1..63 in one persistent kernel
    k_levels<<<256, 512, 0, stream>>>(P, Q, nodeH, nodeL, BTfH, BTfL,
                                      bc, biasBig, table, cnt);
}

// Round 7
// 4228.917 us; speedup vs baseline: 6.8438x; 1.0313x over previous
//
#include <hip/hip_runtime.h>
#include <hip/hip_fp16.h>

// CYK net: L=64, B=32, DIN=D=FFS=512
//   P[cell] = table[cell] @ WcL.T ; Q[cell] = table[cell] @ WcR.T      (stored fp16)
//   node(j,s) = bc + max_k ( P[j,j+k] + Q[j+k+1,j+s] )                 (bf16 hi/lo frag-major)
//   [vals|P|Q] = node @ BigB + biasBig   (bf16x3 MFMA)
// Levels 1..63 in ONE persistent kernel (256 blocks x 512 thr, co-resident).
// R6 -> R7: memory-level parallelism. Node jobs per (j,b) = n*32 (4x waves),
// explicit k-unroll x16 batched loads (512B in flight/wave). Tail levels (n<16):
// k-split KC=4 partial-max + reduce phase, 16-col GEMM tiles (n*96 jobs).

#define Lx 64
#define Bb 32
#define CELLSZ (Bb*512)         // 16384 elems per cell tile

typedef __attribute__((ext_vector_type(8))) short short8v;
typedef __attribute__((ext_vector_type(4))) float f32x4;

__device__ __forceinline__ int tri_idx(int a, int c) {
    return a*Lx - (a*(a-1))/2 + (c - a);
}
__device__ __forceinline__ unsigned short f2bf(float x) {
    unsigned u = __float_as_uint(x);
    unsigned r = (u + 0x7FFFu + ((u >> 16) & 1u)) >> 16;
    return (unsigned short)r;
}
__device__ __forceinline__ float bf2f(unsigned short h) {
    return __uint_as_float((unsigned)h << 16);
}
__device__ __forceinline__ size_t frag_i(int r, int c) {
    return (size_t)(r >> 4)*8192 + (c >> 3)*128 + (r & 15)*8 + (c & 7);
}
__device__ __forceinline__ unsigned pk_add_f16(unsigned a, unsigned b) {
    unsigned r;
    asm("v_pk_add_f16 %0, %1, %2" : "=v"(r) : "v"(a), "v"(b));
    return r;
}
__device__ __forceinline__ unsigned pk_max_f16(unsigned a, unsigned b) {
    unsigned r;
    asm("v_pk_max_f16 %0, %1, %2" : "=v"(r) : "v"(a), "v"(b));
    return r;
}
__device__ __forceinline__ float2 h2_to_f2(unsigned u) {
    __half2 h;
    *reinterpret_cast<unsigned*>(&h) = u;
    return __half22float2(h);
}

// global barrier: release-add once, relaxed spin, single acquire fence at exit.
__device__ __forceinline__ void gbar(int* cnt, int target) {
    __syncthreads();
    if (threadIdx.x == 0) {
        __hip_atomic_fetch_add(cnt, 1, __ATOMIC_RELEASE, __HIP_MEMORY_SCOPE_AGENT);
        while (__hip_atomic_load(cnt, __ATOMIC_RELAXED, __HIP_MEMORY_SCOPE_AGENT) < target)
            __builtin_amdgcn_s_sleep(2);
        __builtin_amdgcn_fence(__ATOMIC_ACQUIRE, "agent");
    }
    __syncthreads();
}

// ---------------- setup kernels ----------------

__global__ void k_zero_lower(float* __restrict__ table) {
    int cell = blockIdx.x >> 4;
    int i = cell >> 6, j = cell & 63;
    if (j >= i) return;
    int sub = blockIdx.x & 15;
    float4* p = (float4*)(table + (size_t)cell*CELLSZ) + sub*256 + threadIdx.x;
    *p = make_float4(0.f,0.f,0.f,0.f);
}

__global__ void k_lengths(const float* __restrict__ xs_mask, float* __restrict__ lengths) {
    int b = threadIdx.x;
    if (b < Bb) {
        float s = 0.f;
        for (int i = 0; i < Lx; ++i) s += xs_mask[i*Bb + b];
        lengths[b] = s;
    }
}

__global__ void k_mask(const float* __restrict__ lengths, float* __restrict__ mask_out) {
    int idx = blockIdx.x*256 + threadIdx.x;
    int b = idx & 31;
    int j = (idx >> 5) & 63;
    int i = idx >> 11;
    mask_out[idx] = (j >= i && (float)j < lengths[b]) ? 1.f : 0.f;
}

__global__ void k_bias(const float* __restrict__ b2, const float* __restrict__ Wc,
                       float* __restrict__ biasBig) {
    int c = blockIdx.x*256 + threadIdx.x;
    if (c >= 1536) return;
    if (c < 512) { biasBig[c] = b2[c]; return; }
    int p = (c - 512) & 511;
    int dofs = (c < 1024) ? 0 : 512;
    float s = 0.f;
    for (int d = 0; d < 512; ++d) s += b2[d] * Wc[p*1024 + dofs + d];
    biasBig[c] = s;
}

__global__ void k_prep_xh(const float* __restrict__ xs_h,
                          unsigned short* __restrict__ xhH, unsigned short* __restrict__ xhL) {
    int gid = blockIdx.x*256 + threadIdx.x;
    int cell = gid >> 14, e = gid & 16383;
    int b = e >> 9, d = e & 511;
    float v = xs_h[gid];
    unsigned short h = f2bf(v);
    size_t fi = (size_t)cell*16384 + frag_i(b, d);
    xhH[fi] = h; xhL[fi] = f2bf(v - bf2f(h));
}

__global__ void k_prep_w1(const float* __restrict__ W1,
                          unsigned short* __restrict__ WH, unsigned short* __restrict__ WL) {
    int gid = blockIdx.x*256 + threadIdx.x;
    int c = gid >> 9, k = gid & 511;
    float v = W1[c*512 + k];
    unsigned short h = f2bf(v);
    size_t fi = frag_i(c, k);
    WH[fi] = h; WL[fi] = f2bf(v - bf2f(h));
}

__global__ void k_prep_b0(const float* __restrict__ Wc,
                          unsigned short* __restrict__ BH, unsigned short* __restrict__ BL) {
    int gid = blockIdx.x*256 + threadIdx.x;
    int c = gid >> 9, k = gid & 511;
    float v = (c < 512) ? Wc[c*1024 + k] : Wc[(c-512)*1024 + 512 + k];
    unsigned short h = f2bf(v);
    size_t fi = frag_i(c, k);
    BH[fi] = h; BL[fi] = f2bf(v - bf2f(h));
}

__global__ void k_gemm_M(const float* __restrict__ W2, const float* __restrict__ Wc,
                         float* __restrict__ BigB) {
    __shared__ float W2s[32][33];
    __shared__ float Wcs[32][33];
    int ftile = blockIdx.x & 15;
    int ptile = blockIdx.x >> 4;
    int f0 = ftile*32, p0 = ptile*32;
    int dofs  = (p0 >= 512) ? 512 : 0;
    int prow0 = (p0 >= 512) ? (p0 - 512) : p0;
    int t = threadIdx.x;
    int ff = t & 31, pg = t >> 5;
    float acc[4] = {0,0,0,0};
    for (int d0 = 0; d0 < 512; d0 += 32) {
        __syncthreads();
        #pragma unroll
        for (int i = 0; i < 4; ++i) {
            int e = t + 256*i;
            int r = e >> 5, cc = e & 31;
            W2s[r][cc] = W2[(d0 + r)*512 + f0 + cc];
            Wcs[r][cc] = Wc[(prow0 + r)*1024 + dofs + d0 + cc];
        }
        __syncthreads();
        #pragma unroll
        for (int dd = 0; dd < 32; ++dd) {
            float w = W2s[dd][ff];
            #pragma unroll
            for (int ii = 0; ii < 4; ++ii)
                acc[ii] += w * Wcs[pg*4 + ii][dd];
        }
    }
    #pragma unroll
    for (int ii = 0; ii < 4; ++ii)
        BigB[(f0 + ff)*1536 + 512 + p0 + pg*4 + ii] = acc[ii];
}

__global__ void k_makeBT(const float* __restrict__ W2, const float* __restrict__ BigB,
                         unsigned short* __restrict__ BTfH, unsigned short* __restrict__ BTfL) {
    int gid = blockIdx.x*256 + threadIdx.x;
    int c = gid >> 9, k = gid & 511;
    float v = (c < 512) ? W2[c*512 + k] : BigB[k*1536 + c];
    unsigned short h = f2bf(v);
    size_t fi = frag_i(c, k);
    BTfH[fi] = h; BTfL[fi] = f2bf(v - bf2f(h));
}

// ---------------- level-0 MFMA GEMMs ----------------
template<int MODE, int NCOLS>
__global__ __launch_bounds__(256) void k_mfma(
    const unsigned short* __restrict__ AH, const unsigned short* __restrict__ AL,
    const unsigned short* __restrict__ BH, const unsigned short* __restrict__ BL,
    const float* __restrict__ bias,
    float* __restrict__ table, __half* __restrict__ P, __half* __restrict__ Q,
    unsigned short* __restrict__ outH, unsigned short* __restrict__ outL)
{
    constexpr int CTILES = NCOLS / 256;
    int cell = blockIdx.x / CTILES;
    int ct   = blockIdx.x % CTILES;
    int t = threadIdx.x;
    int w = t >> 6, l = t & 63;
    int l15 = l & 15, lg = l >> 4;
    int c0 = ct*256 + w*64;

    f32x4 acc[2][4];
    #pragma unroll
    for (int i = 0; i < 2; ++i)
        #pragma unroll
        for (int j = 0; j < 4; ++j) acc[i][j] = (f32x4){0.f,0.f,0.f,0.f};

    size_t lane_off = (size_t)lg*128 + l15*8;
    const unsigned short* aH = AH + (size_t)cell*16384 + lane_off;
    const unsigned short* aL = AL + (size_t)cell*16384 + lane_off;
    const unsigned short* bH = BH + (size_t)(c0 >> 4)*8192 + lane_off;
    const unsigned short* bL = BL + (size_t)(c0 >> 4)*8192 + lane_off;

    #pragma unroll 2
    for (int ks = 0; ks < 16; ++ks) {
        int ko = ks * 512;
        short8v ah0 = *(const short8v*)(aH + ko);
        short8v ah1 = *(const short8v*)(aH + ko + 8192);
        short8v al0 = *(const short8v*)(aL + ko);
        short8v al1 = *(const short8v*)(aL + ko + 8192);
        short8v bh[4], bl[4];
        #pragma unroll
        for (int cf = 0; cf < 4; ++cf) {
            bh[cf] = *(const short8v*)(bH + ko + cf*8192);
            bl[cf] = *(const short8v*)(bL + ko + cf*8192);
        }
        #pragma unroll
        for (int cf = 0; cf < 4; ++cf) {
            acc[0][cf] = __builtin_amdgcn_mfma_f32_16x16x32_bf16(ah0, bh[cf], acc[0][cf], 0, 0, 0);
            acc[1][cf] = __builtin_amdgcn_mfma_f32_16x16x32_bf16(ah1, bh[cf], acc[1][cf], 0, 0, 0);
            acc[0][cf] = __builtin_amdgcn_mfma_f32_16x16x32_bf16(al0, bh[cf], acc[0][cf], 0, 0, 0);
            acc[1][cf] = __builtin_amdgcn_mfma_f32_16x16x32_bf16(al1, bh[cf], acc[1][cf], 0, 0, 0);
            acc[0][cf] = __builtin_amdgcn_mfma_f32_16x16x32_bf16(ah0, bl[cf], acc[0][cf], 0, 0, 0);
            acc[1][cf] = __builtin_amdgcn_mfma_f32_16x16x32_bf16(ah1, bl[cf], acc[1][cf], 0, 0, 0);
        }
    }

    #pragma unroll
    for (int cf = 0; cf < 4; ++cf) {
        int c = c0 + cf*16 + l15;
        if (MODE == 0) {
            float bv = bias[c];
            size_t tbl = (size_t)(cell*65)*CELLSZ;
            #pragma unroll
            for (int rb = 0; rb < 2; ++rb)
                #pragma unroll
                for (int j = 0; j < 4; ++j) {
                    int r = rb*16 + lg*4 + j;
                    float v = acc[rb][cf][j] + bv;
                    table[tbl + (size_t)r*512 + c] = v;
                    size_t fi = (size_t)cell*16384 + frag_i(r, c);
                    unsigned short h = f2bf(v);
                    outH[fi] = h; outL[fi] = f2bf(v - bf2f(h));
                }
        } else {
            int tc = tri_idx(cell, cell);
            __half* dst = (c < 512) ? (P + (size_t)tc*CELLSZ) : (Q + (size_t)tc*CELLSZ);
            int cc = c & 511;
            #pragma unroll
            for (int rb = 0; rb < 2; ++rb)
                #pragma unroll
                for (int j = 0; j < 4; ++j) {
                    int r = rb*16 + lg*4 + j;
                    dst[(size_t)r*512 + cc] = __float2half(acc[rb][cf][j]);
                }
        }
    }
}

// ---------------- persistent level loop ----------------
// grid = 256 blocks x 512 threads (8 waves, 2048 waves total).
__global__ __launch_bounds__(512) void k_levels(
    __half* __restrict__ P, __half* __restrict__ Q,
    unsigned short* __restrict__ nodeH, unsigned short* __restrict__ nodeL,
    __half* __restrict__ nodePart,
    const unsigned short* __restrict__ BTfH, const unsigned short* __restrict__ BTfL,
    const float* __restrict__ bc, const float* __restrict__ biasBig,
    float* __restrict__ table, int* __restrict__ cnt)
{
    const int nW = gridDim.x << 3;
    int wave = (blockIdx.x << 3) | (threadIdx.x >> 6);
    int l = threadIdx.x & 63;
    int l15 = l & 15, lg = l >> 4;
    int bar = 0;
    const int nB = gridDim.x;

    for (int s = 1; s < 64; ++s) {
        int n = 64 - s;

        // ================= node max accumulation core (per (j,b), lane owns 8 f) ======
        // main path: full k range, writes frag-major hi/lo directly.
        // KC path (n<16): k-chunk, writes packed f16 partial.
        if (n >= 16) {
            // ---- node phase: jobs n*32 : j = q>>5, b = q&31 ----
            for (int q = wave; q < n*32; q += nW) {
                int j = q >> 5, b = q & 31;
                int f0 = l*8;
                unsigned a0 = 0xFC00FC00u, a1 = a0, a2 = a0, a3 = a0;
                int basePt = tri_idx(j, j);
                const __half* Pb = P + (size_t)basePt*CELLSZ + b*512 + f0;
                const __half* Qb = Q + b*512 + f0;
                int k = 0;
                while (k + 16 <= s) {
                    uint4 vp[16], vq[16];
                    #pragma unroll
                    for (int u = 0; u < 16; ++u) {
                        vp[u] = *(const uint4*)(Pb + (size_t)(k+u)*CELLSZ);
                        int aa = j + k + u + 1;
                        int tQ = aa*64 - ((aa*(aa-1)) >> 1) + (j + s - aa);
                        vq[u] = *(const uint4*)(Qb + (size_t)tQ*CELLSZ);
                    }
                    #pragma unroll
                    for (int u = 0; u < 16; ++u) {
                        a0 = pk_max_f16(a0, pk_add_f16(vp[u].x, vq[u].x));
                        a1 = pk_max_f16(a1, pk_add_f16(vp[u].y, vq[u].y));
                        a2 = pk_max_f16(a2, pk_add_f16(vp[u].z, vq[u].z));
                        a3 = pk_max_f16(a3, pk_add_f16(vp[u].w, vq[u].w));
                    }
                    k += 16;
                }
                for (; k < s; ++k) {
                    uint4 vp = *(const uint4*)(Pb + (size_t)k*CELLSZ);
                    int aa = j + k + 1;
                    int tQ = aa*64 - ((aa*(aa-1)) >> 1) + (j + s - aa);
                    uint4 vq = *(const uint4*)(Qb + (size_t)tQ*CELLSZ);
                    a0 = pk_max_f16(a0, pk_add_f16(vp.x, vq.x));
                    a1 = pk_max_f16(a1, pk_add_f16(vp.y, vq.y));
                    a2 = pk_max_f16(a2, pk_add_f16(vp.z, vq.z));
                    a3 = pk_max_f16(a3, pk_add_f16(vp.w, vq.w));
                }
                // epilogue: + bc, bf16 hi/lo, frag-major write
                float4 bcA = *(const float4*)(bc + f0);
                float4 bcB = *(const float4*)(bc + f0 + 4);
                float bcv[8] = {bcA.x,bcA.y,bcA.z,bcA.w,bcB.x,bcB.y,bcB.z,bcB.w};
                unsigned am[4] = {a0,a1,a2,a3};
                unsigned uh[4], ul[4];
                #pragma unroll
                for (int e = 0; e < 4; ++e) {
                    float2 x = h2_to_f2(am[e]);
                    float v0 = x.x + bcv[2*e], v1 = x.y + bcv[2*e+1];
                    unsigned short h0 = f2bf(v0), h1 = f2bf(v1);
                    unsigned short o0 = f2bf(v0 - bf2f(h0)), o1 = f2bf(v1 - bf2f(h1));
                    uh[e] = (unsigned)h0 | ((unsigned)h1 << 16);
                    ul[e] = (unsigned)o0 | ((unsigned)o1 << 16);
                }
                size_t fi = (size_t)j*16384 + frag_i(b, f0);
                *(uint4*)(nodeH + fi) = make_uint4(uh[0],uh[1],uh[2],uh[3]);
                *(uint4*)(nodeL + fi) = make_uint4(ul[0],ul[1],ul[2],ul[3]);
            }
            gbar(cnt, (++bar)*nB);

            // ---- gemm phase (64-col tiles): jobs n*24 ----
            for (int q = wave; q < n*24; q += nW) {
                int cell = q / 24;
                int ct   = q - cell*24;
                int c0   = ct*64;

                f32x4 acc[2][4];
                #pragma unroll
                for (int i = 0; i < 2; ++i)
                    #pragma unroll
                    for (int j2 = 0; j2 < 4; ++j2) acc[i][j2] = (f32x4){0.f,0.f,0.f,0.f};

                size_t lane_off = (size_t)lg*128 + l15*8;
                const unsigned short* aH = nodeH + (size_t)cell*16384 + lane_off;
                const unsigned short* aL = nodeL + (size_t)cell*16384 + lane_off;
                const unsigned short* bH = BTfH + (size_t)(c0 >> 4)*8192 + lane_off;
                const unsigned short* bL = BTfL + (size_t)(c0 >> 4)*8192 + lane_off;

                #pragma unroll 2
                for (int ks = 0; ks < 16; ++ks) {
                    int ko = ks * 512;
                    short8v ah0 = *(const short8v*)(aH + ko);
                    short8v ah1 = *(const short8v*)(aH + ko + 8192);
                    short8v al0 = *(const short8v*)(aL + ko);
                    short8v al1 = *(const short8v*)(aL + ko + 8192);
                    short8v bh[4], bl[4];
                    #pragma unroll
                    for (int cf = 0; cf < 4; ++cf) {
                        bh[cf] = *(const short8v*)(bH + ko + cf*8192);
                        bl[cf] = *(const short8v*)(bL + ko + cf*8192);
                    }
                    #pragma unroll
                    for (int cf = 0; cf < 4; ++cf) {
                        acc[0][cf] = __builtin_amdgcn_mfma_f32_16x16x32_bf16(ah0, bh[cf], acc[0][cf], 0, 0, 0);
                        acc[1][cf] = __builtin_amdgcn_mfma_f32_16x16x32_bf16(ah1, bh[cf], acc[1][cf], 0, 0, 0);
                        acc[0][cf] = __builtin_amdgcn_mfma_f32_16x16x32_bf16(al0, bh[cf], acc[0][cf], 0, 0, 0);
                        acc[1][cf] = __builtin_amdgcn_mfma_f32_16x16x32_bf16(al1, bh[cf], acc[1][cf], 0, 0, 0);
                        acc[0][cf] = __builtin_amdgcn_mfma_f32_16x16x32_bf16(ah0, bl[cf], acc[0][cf], 0, 0, 0);
                        acc[1][cf] = __builtin_amdgcn_mfma_f32_16x16x32_bf16(ah1, bl[cf], acc[1][cf], 0, 0, 0);
                    }
                }

                int tc = tri_idx(cell, cell) + s;
                size_t tbl = (size_t)(cell*64 + cell + s)*CELLSZ;
                #pragma unroll
                for (int cf = 0; cf < 4; ++cf) {
                    int c = c0 + cf*16 + l15;
                    float bv = biasBig[c];
                    #pragma unroll
                    for (int rb = 0; rb < 2; ++rb)
                        #pragma unroll
                        for (int j2 = 0; j2 < 4; ++j2) {
                            int r = rb*16 + lg*4 + j2;
                            float v = acc[rb][cf][j2] + bv;
                            if (c < 512)       table[tbl + (size_t)r*512 + c] = v;
                            else if (c < 1024) P[(size_t)tc*CELLSZ + (size_t)r*512 + (c-512)]  = __float2half(v);
                            else               Q[(size_t)tc*CELLSZ + (size_t)r*512 + (c-1024)] = __float2half(v);
                        }
                }
            }
            gbar(cnt, (++bar)*nB);
        } else {
            // ================= tail levels (n < 16): 3 phases =================
            // ---- node partial: jobs n*128 : j = q>>7, kc = (q>>5)&3, b = q&31 ----
            for (int q = wave; q < n*128; q += nW) {
                int j  = q >> 7;
                int kc = (q >> 5) & 3;
                int b  = q & 31;
                int f0 = l*8;
                int k0 = (s*kc) >> 2, k1 = (s*(kc+1)) >> 2;
                unsigned a0 = 0xFC00FC00u, a1 = a0, a2 = a0, a3 = a0;
                int basePt = tri_idx(j, j);
                const __half* Pb = P + (size_t)basePt*CELLSZ + b*512 + f0;
                const __half* Qb = Q + b*512 + f0;
                int k = k0;
                while (k + 8 <= k1) {
                    uint4 vp[8], vq[8];
                    #pragma unroll
                    for (int u = 0; u < 8; ++u) {
                        vp[u] = *(const uint4*)(Pb + (size_t)(k+u)*CELLSZ);
                        int aa = j + k + u + 1;
                        int tQ = aa*64 - ((aa*(aa-1)) >> 1) + (j + s - aa);
                        vq[u] = *(const uint4*)(Qb + (size_t)tQ*CELLSZ);
                    }
                    #pragma unroll
                    for (int u = 0; u < 8; ++u) {
                        a0 = pk_max_f16(a0, pk_add_f16(vp[u].x, vq[u].x));
                        a1 = pk_max_f16(a1, pk_add_f16(vp[u].y, vq[u].y));
                        a2 = pk_max_f16(a2, pk_add_f16(vp[u].z, vq[u].z));
                        a3 = pk_max_f16(a3, pk_add_f16(vp[u].w, vq[u].w));
                    }
                    k += 8;
                }
                for (; k < k1; ++k) {
                    uint4 vp = *(const uint4*)(Pb + (size_t)k*CELLSZ);
                    int aa = j + k + 1;
                    int tQ = aa*64 - ((aa*(aa-1)) >> 1) + (j + s - aa);
                    uint4 vq = *(const uint4*)(Qb + (size_t)tQ*CELLSZ);
                    a0 = pk_max_f16(a0, pk_add_f16(vp.x, vq.x));
                    a1 = pk_max_f16(a1, pk_add_f16(vp.y, vq.y));
                    a2 = pk_max_f16(a2, pk_add_f16(vp.z, vq.z));
                    a3 = pk_max_f16(a3, pk_add_f16(vp.w, vq.w));
                }
                *(uint4*)(nodePart + (size_t)(kc*16 + j)*CELLSZ + b*512 + f0) =
                    make_uint4(a0, a1, a2, a3);
            }
            gbar(cnt, (++bar)*nB);

            // ---- node reduce: jobs n*32 ----
            for (int q = wave; q < n*32; q += nW) {
                int j = q >> 5, b = q & 31;
                int f0 = l*8;
                size_t off = (size_t)b*512 + f0;
                uint4 c0v = *(const uint4*)(nodePart + (size_t)(0*16 + j)*CELLSZ + off);
                uint4 c1v = *(const uint4*)(nodePart + (size_t)(1*16 + j)*CELLSZ + off);
                uint4 c2v = *(const uint4*)(nodePart + (size_t)(2*16 + j)*CELLSZ + off);
                uint4 c3v = *(const uint4*)(nodePart + (size_t)(3*16 + j)*CELLSZ + off);
                unsigned a0 = pk_max_f16(pk_max_f16(c0v.x, c1v.x), pk_max_f16(c2v.x, c3v.x));
                unsigned a1 = pk_max_f16(pk_max_f16(c0v.y, c1v.y), pk_max_f16(c2v.y, c3v.y));
                unsigned a2 = pk_max_f16(pk_max_f16(c0v.z, c1v.z), pk_max_f16(c2v.z, c3v.z));
                unsigned a3 = pk_max_f16(pk_max_f16(c0v.w, c1v.w), pk_max_f16(c2v.w, c3v.w));
                float4 bcA = *(const float4*)(bc + f0);
                float4 bcB = *(const float4*)(bc + f0 + 4);
                float bcv[8] = {bcA.x,bcA.y,bcA.z,bcA.w,bcB.x,bcB.y,bcB.z,bcB.w};
                unsigned am[4] = {a0,a1,a2,a3};
                unsigned uh[4], ul[4];
                #pragma unroll
                for (int e = 0; e < 4; ++e) {
                    float2 x = h2_to_f2(am[e]);
                    float v0 = x.x + bcv[2*e], v1 = x.y + bcv[2*e+1];
                    unsigned short h0 = f2bf(v0), h1 = f2bf(v1);
                    unsigned short o0 = f2bf(v0 - bf2f(h0)), o1 = f2bf(v1 - bf2f(h1));
                    uh[e] = (unsigned)h0 | ((unsigned)h1 << 16);
                    ul[e] = (unsigned)o0 | ((unsigned)o1 << 16);
                }
                size_t fi = (size_t)j*16384 + frag_i(b, f0);
                *(uint4*)(nodeH + fi) = make_uint4(uh[0],uh[1],uh[2],uh[3]);
                *(uint4*)(nodeL + fi) = make_uint4(ul[0],ul[1],ul[2],ul[3]);
            }
            gbar(cnt, (++bar)*nB);

            // ---- gemm phase (16-col tiles): jobs n*96, explicit 4-deep ks batch ----
            for (int q = wave; q < n*96; q += nW) {
                int cell = q / 96;
                int cf16 = q - cell*96;
                int c0   = cf16*16;

                f32x4 acc0 = (f32x4){0.f,0.f,0.f,0.f};
                f32x4 acc1 = (f32x4){0.f,0.f,0.f,0.f};

                size_t lane_off = (size_t)lg*128 + l15*8;
                const unsigned short* aH = nodeH + (size_t)cell*16384 + lane_off;
                const unsigned short* aL = nodeL + (size_t)cell*16384 + lane_off;
                const unsigned short* bH = BTfH + (size_t)cf16*8192 + lane_off;
                const unsigned short* bL = BTfL + (size_t)cf16*8192 + lane_off;

                for (int ksb = 0; ksb < 16; ksb += 4) {
                    short8v ah0[4], ah1[4], al0[4], al1[4], bh[4], bl[4];
                    #pragma unroll
                    for (int u = 0; u < 4; ++u) {
                        int ko = (ksb + u) * 512;
                        ah0[u] = *(const short8v*)(aH + ko);
                        ah1[u] = *(const short8v*)(aH + ko + 8192);
                        al0[u] = *(const short8v*)(aL + ko);
                        al1[u] = *(const short8v*)(aL + ko + 8192);
                        bh[u]  = *(const short8v*)(bH + ko);
                        bl[u]  = *(const short8v*)(bL + ko);
                    }
                    #pragma unroll
                    for (int u = 0; u < 4; ++u) {
                        acc0 = __builtin_amdgcn_mfma_f32_16x16x32_bf16(ah0[u], bh[u], acc0, 0, 0, 0);
                        acc1 = __builtin_amdgcn_mfma_f32_16x16x32_bf16(ah1[u], bh[u], acc1, 0, 0, 0);
                        acc0 = __builtin_amdgcn_mfma_f32_16x16x32_bf16(al0[u], bh[u], acc0, 0, 0, 0);
                        acc1 = __builtin_amdgcn_mfma_f32_16x16x32_bf16(al1[u], bh[u], acc1, 0, 0, 0);
                        acc0 = __builtin_amdgcn_mfma_f32_16x16x32_bf16(ah0[u], bl[u], acc0, 0, 0, 0);
                        acc1 = __builtin_amdgcn_mfma_f32_16x16x32_bf16(ah1[u], bl[u], acc1, 0, 0, 0);
                    }
                }

                int c = c0 + l15;
                float bv = biasBig[c];
                int tc = tri_idx(cell, cell) + s;
                size_t tbl = (size_t)(cell*64 + cell + s)*CELLSZ;
                #pragma unroll
                for (int rb = 0; rb < 2; ++rb) {
                    f32x4 av = rb ? acc1 : acc0;
                    #pragma unroll
                    for (int j2 = 0; j2 < 4; ++j2) {
                        int r = rb*16 + lg*4 + j2;
                        float v = av[j2] + bv;
                        if (c < 512)       table[tbl + (size_t)r*512 + c] = v;
                        else if (c < 1024) P[(size_t)tc*CELLSZ + (size_t)r*512 + (c-512)]  = __float2half(v);
                        else               Q[(size_t)tc*CELLSZ + (size_t)r*512 + (c-1024)] = __float2half(v);
                    }
                }
            }
            gbar(cnt, (++bar)*nB);
        }
    }
}

// ---------------- launch ----------------

extern "C" void kernel_launch(void* const* d_in, const int* in_sizes, int n_in,
                              void* d_out, int out_size, void* d_ws, size_t ws_size,
                              hipStream_t stream) {
    const float* xs_h    = (const float*)d_in[0];
    const float* xs_mask = (const float*)d_in[1];
    const float* W1      = (const float*)d_in[2];
    const float* b1      = (const float*)d_in[3];
    const float* Wc      = (const float*)d_in[4];
    const float* bc      = (const float*)d_in[5];
    const float* W2      = (const float*)d_in[6];
    const float* b2      = (const float*)d_in[7];

    float* table   = (float*)d_out;                     // 64*64*32*512 f32
    float* maskout = table + 67108864;                  // 64*64*32

    __half* P = (__half*)d_ws;                          // 2080*16384 halves
    __half* Q = P + 34078720;
    unsigned short* nodeH = (unsigned short*)(Q + 34078720);   // 63*16384
    unsigned short* nodeL = nodeH + 1032192;
    unsigned short* xhH   = nodeL + 1032192;            // 64*16384
    unsigned short* xhL   = xhH + 1048576;
    unsigned short* diagH = xhL + 1048576;              // 64*16384
    unsigned short* diagL = diagH + 1048576;
    unsigned short* W1fH  = diagL + 1048576;            // 512*512
    unsigned short* W1fL  = W1fH + 262144;
    unsigned short* B0fH  = W1fL + 262144;              // 1024*512
    unsigned short* B0fL  = B0fH + 524288;
    unsigned short* BTfH  = B0fL + 524288;              // 1536*512
    unsigned short* BTfL  = BTfH + 786432;
    float* BigB    = (float*)(BTfL + 786432);           // 512*1536 f32
    float* biasBig = BigB + 786432;                     // 1536
    float* lengths = biasBig + 1536;                    // 32
    int*   cnt     = (int*)(lengths + 32);              // global barrier counter
    __half* nodePart = (__half*)(cnt + 16);             // 64*16384 halves (KC partials)

    (void)hipMemsetAsync(cnt, 0, 4, stream);
    k_zero_lower<<<65536, 256, 0, stream>>>(table);
    k_lengths<<<1, 64, 0, stream>>>(xs_mask, lengths);
    k_mask<<<512, 256, 0, stream>>>(lengths, maskout);
    k_prep_xh<<<4096, 256, 0, stream>>>(xs_h, xhH, xhL);
    k_prep_w1<<<1024, 256, 0, stream>>>(W1, W1fH, W1fL);
    k_prep_b0<<<2048, 256, 0, stream>>>(Wc, B0fH, B0fL);
    k_gemm_M<<<512, 256, 0, stream>>>(W2, Wc, BigB);
    k_bias<<<6, 256, 0, stream>>>(b2, Wc, biasBig);
    k_makeBT<<<3072, 256, 0, stream>>>(W2, BigB, BTfH, BTfL);

    // level 0: diag (emits frag-major diag too), then P/Q projections
    k_mfma<0, 512><<<64*2, 256, 0, stream>>>(xhH, xhL, W1fH, W1fL, b1,
                                             table, nullptr, nullptr, diagH, diagL);
    k_mfma<1, 1024><<<64*4, 256, 0, stream>>>(diagH, diagL, B0fH, B0fL, nullptr,
                                              table, P, Q, nullptr, nullptr);

    // levels 1..63 in one persistent kernel
    k_levels<<<256, 512, 0, stream>>>(P, Q, nodeH, nodeL, nodePart, BTfH, BTfL,
                                      bc, biasBig, table, cnt);
}